// Round 4
// baseline (516.222 us; speedup 1.0000x reference)
//
#include <hip/hip_runtime.h>
#include <hip/hip_bf16.h>

#define Bb 4
#define Hh 8
#define Ll 8192
#define Dd 64
#define Cc 256
#define Ww 32
#define TL 128   // tokens per k1 block

// ---------------- k1: dists GEMM + argmax buckets + loss partials + dist_T write ----------------
// grid (Ll/TL, hStep), block 256. thread tile: 8 tokens x 8 clusters.
// x tile in LDS (ds_read_b128); means rows read from global (L1-resident, broadcast-4 per instr).
__global__ __launch_bounds__(256, 3) void k1_gemm(const float* __restrict__ x,
                                                  const float* __restrict__ means,
                                                  float* __restrict__ distT,
                                                  int* __restrict__ buckets,
                                                  float* __restrict__ lossP,
                                                  int b, int h0) {
    __shared__ __align__(16) float xs[TL * 68];    // 34 KB token tile
    __shared__ float pv[TL * 4];
    __shared__ int   pc[TL * 4];
    __shared__ float msq[256];
    __shared__ float lossAcc;

    const int tid = threadIdx.x;
    const int hl  = blockIdx.y;
    const int h   = h0 + hl;
    const int l0  = blockIdx.x * TL;
    const int tg  = tid & 15;    // tokens t = tg + 16*jt, jt<8
    const int cg  = tid >> 4;    // clusters c = cg + 16*jl + 128*p, jl<8

    if (tid == 0) lossAcc = 0.f;

    const float* xbase = x + (((size_t)(b * Hh + h)) * Ll + l0) * Dd;
    for (int j = tid; j < TL * 16; j += 256) {
        int t = j >> 4, k4 = (j & 15) << 2;
        *(float4*)&xs[t * 68 + k4] = *(const float4*)(xbase + t * Dd + k4);
    }

    const float* mh = means + (size_t)h * Cc * Dd;
    {   // |m_c|^2 for the loss (one row per thread)
        const float* mr = mh + tid * Dd;
        float s = 0.f;
        #pragma unroll
        for (int k = 0; k < 64; k += 4) {
            float4 m = *(const float4*)(mr + k);
            s = fmaf(m.x, m.x, s); s = fmaf(m.y, m.y, s);
            s = fmaf(m.z, m.z, s); s = fmaf(m.w, m.w, s);
        }
        msq[tid] = s;
    }
    __syncthreads();

    float bvr[8]; int bcr[8];
    #pragma unroll
    for (int jt = 0; jt < 8; jt++) { bvr[jt] = -3.4e38f; bcr[jt] = 0; }

    const size_t pbase = (size_t)hl * Cc;

    for (int p = 0; p < 2; p++) {
        float acc[8][8];
        #pragma unroll
        for (int jt = 0; jt < 8; jt++)
            #pragma unroll
            for (int jl = 0; jl < 8; jl++) acc[jt][jl] = 0.f;

        const float* mp = mh + (cg + (p << 7)) * Dd;

        #pragma unroll 2
        for (int k = 0; k < 64; k += 4) {
            float4 xa[8];
            #pragma unroll
            for (int jt = 0; jt < 8; jt++) xa[jt] = *(const float4*)&xs[(tg + 16 * jt) * 68 + k];
            #pragma unroll
            for (int jl = 0; jl < 8; jl++) {
                float4 m = *(const float4*)(mp + jl * (16 * Dd) + k);
                #pragma unroll
                for (int jt = 0; jt < 8; jt++) {
                    float a = acc[jt][jl];
                    a = fmaf(xa[jt].x, m.x, a); a = fmaf(xa[jt].y, m.y, a);
                    a = fmaf(xa[jt].z, m.z, a); a = fmaf(xa[jt].w, m.w, a);
                    acc[jt][jl] = a;
                }
            }
        }

        // dist_T writes + running per-thread argmax (c strictly ascending across jl and p)
        #pragma unroll
        for (int jt = 0; jt < 8; jt++) {
            int t = tg + 16 * jt;
            #pragma unroll
            for (int jl = 0; jl < 8; jl++) {
                int cl = cg + 16 * jl + (p << 7);
                float v = acc[jt][jl];
                distT[(pbase + cl) * Ll + l0 + t] = v;
                if (v > bvr[jt]) { bvr[jt] = v; bcr[jt] = cl; }
            }
        }
    }

    // merge argmax: in-wave across the 4 cluster-groups of this wave, then LDS across waves
    #pragma unroll
    for (int jt = 0; jt < 8; jt++) {
        float bv = bvr[jt]; int bc = bcr[jt];
        #pragma unroll
        for (int off = 16; off <= 32; off <<= 1) {
            float ov = __shfl_xor(bv, off);
            int   oc = __shfl_xor(bc, off);
            if (ov > bv || (ov == bv && oc < bc)) { bv = ov; bc = oc; }
        }
        if ((tid & 48) == 0) { int t = tg + 16 * jt; pv[t * 4 + (tid >> 6)] = bv; pc[t * 4 + (tid >> 6)] = bc; }
    }
    __syncthreads();

    if (tid < TL) {
        int t = tid;
        float bv = pv[t * 4]; int bc = pc[t * 4];
        #pragma unroll
        for (int g = 1; g < 4; g++) {
            float v = pv[t * 4 + g]; int c2 = pc[t * 4 + g];
            if (v > bv || (v == bv && c2 < bc)) { bv = v; bc = c2; }
        }
        float ss = 0.f;
        #pragma unroll
        for (int k = 0; k < 64; k += 4) {
            float4 u = *(const float4*)&xs[t * 68 + k];
            ss = fmaf(u.x, u.x, ss); ss = fmaf(u.y, u.y, ss);
            ss = fmaf(u.z, u.z, ss); ss = fmaf(u.w, u.w, ss);
        }
        buckets[((size_t)(b * Hh + h)) * Ll + l0 + t] = bc;
        atomicAdd(&lossAcc, ss - 2.f * bv + msq[bc]);
    }
    __syncthreads();
    if (tid == 0) lossP[(b * Hh + h) * (Ll / TL) + blockIdx.x] = lossAcc;
}

// ---------------- k2: exact top-32 per (h,c) column via 3-pass (11/11/10-bit) radix select ----------------
__device__ __forceinline__ unsigned int f2key(float f) {
    unsigned int u = __float_as_uint(f);
    return (u & 0x80000000u) ? ~u : (u | 0x80000000u);
}

__global__ __launch_bounds__(256) void k2_topk(const float* __restrict__ distT,
                                               float* __restrict__ outIdx,
                                               int b, int h0) {
    __shared__ unsigned int hist[2048];
    __shared__ unsigned int tsum[256];
    __shared__ unsigned int gsum[16];
    __shared__ unsigned int sA, sPrefix, sNA, sEq;
    __shared__ int aboveList[32];
    __shared__ int eqList[64];
    __shared__ int comb[32];

    const int tid = threadIdx.x;
    const int c = blockIdx.x, hl = blockIdx.y;
    const int h = h0 + hl;
    const float* col = distT + ((size_t)(hl * Cc + c)) * Ll;

    unsigned int key[32];
    #pragma unroll
    for (int j = 0; j < 8; j++) {
        float4 v = *(const float4*)(col + j * 1024 + tid * 4);
        key[j * 4 + 0] = f2key(v.x); key[j * 4 + 1] = f2key(v.y);
        key[j * 4 + 2] = f2key(v.z); key[j * 4 + 3] = f2key(v.w);
    }
    if (tid == 0) { sA = 0; sPrefix = 0; }

    #pragma unroll
    for (int pass = 0; pass < 3; pass++) {
        const int shift = (pass == 0) ? 21 : (pass == 1) ? 10 : 0;
        const int width = (pass == 2) ? 10 : 11;
        const int bins = 1 << width;
        const unsigned maskHi = (pass == 0) ? 0u : (0xFFFFFFFFu << (shift + width));
        for (int j = tid; j < bins; j += 256) hist[j] = 0;
        __syncthreads();
        const unsigned A = sA, pref = sPrefix;
        #pragma unroll
        for (int j = 0; j < 32; j++)
            if (((key[j] ^ pref) & maskHi) == 0)
                atomicAdd(&hist[(key[j] >> shift) & (bins - 1)], 1u);
        __syncthreads();
        const int bpt = bins >> 8;       // bins per thread: 8,8,4
        unsigned s = 0;
        for (int q = 0; q < bpt; q++) s += hist[tid * bpt + q];
        tsum[tid] = s;
        __syncthreads();
        if (tid < 16) { unsigned g2 = 0; for (int q = 0; q < 16; q++) g2 += tsum[tid * 16 + q]; gsum[tid] = g2; }
        __syncthreads();
        unsigned St = 0;
        {   int g = tid >> 4;
            for (int t2 = tid + 1; t2 < (g + 1) * 16; t2++) St += tsum[t2];
            for (int g2 = g + 1; g2 < 16; g2++) St += gsum[g2]; }
        unsigned sufAfter = St;          // suffix-exclusive of this thread's top bin
        for (int q = bpt - 1; q >= 0; q--) {
            int D = tid * bpt + q;
            unsigned hd = hist[D];
            unsigned sufIncl = sufAfter + hd;
            bool cond = (A + sufIncl) >= Ww;
            bool condNext = (A + sufAfter) >= Ww;
            if (cond && !condNext) { sA = A + sufAfter; sPrefix = pref | ((unsigned)D << shift); }
            sufAfter = sufIncl;
        }
        __syncthreads();
    }

    const unsigned T = sPrefix;
    const int r = Ww - (int)sA;
    if (tid == 0) { sNA = 0; sEq = 0; }
    __syncthreads();
    #pragma unroll
    for (int j = 0; j < 32; j++) {
        unsigned kk = key[j];
        int idx = (j >> 2) * 1024 + tid * 4 + (j & 3);
        if (kk > T) {
            int p2 = (int)atomicAdd(&sNA, 1u);
            if (p2 < 32) aboveList[p2] = idx;
        } else if (kk == T) {
            int p2 = (int)atomicAdd(&sEq, 1u);
            if (p2 < 64) eqList[p2] = idx;
        }
    }
    __syncthreads();
    const int nA = (int)sNA;
    const int eq = (int)sEq;
    if (eq <= 64) {
        if (tid < eq) {
            int v = eqList[tid];
            int rank = 0;
            for (int j = 0; j < eq; j++) rank += (eqList[j] < v);
            if (rank < r) comb[nA + rank] = v;
        }
    } else if (tid == 0) {  // pathological tie flood: serial, correct
        int taken = 0;
        for (int i = 0; i < Ll && taken < r; i++)
            if (f2key(col[i]) == T) comb[nA + taken++] = i;
    }
    if (tid < nA) comb[tid] = aboveList[tid];
    __syncthreads();
    if (tid < Ww) {
        int v = comb[tid];
        int rank = 0;
        #pragma unroll
        for (int j = 0; j < Ww; j++) rank += (comb[j] < v);
        outIdx[(((size_t)(b * Hh + h)) * Cc + c) * Ww + rank] = (float)v;
    }
}

// ---------------- k3: counting sort by (h,cluster), then gather ----------------
__global__ __launch_bounds__(256) void k3_hist(const int* __restrict__ buckets,
                                               unsigned int* __restrict__ hist) {
    __shared__ unsigned int lh[256];
    const int tid = threadIdx.x;
    lh[tid] = 0;
    __syncthreads();
    int i = blockIdx.x * 256 + tid;
    int bk = buckets[i];
    atomicAdd(&lh[bk], 1u);
    __syncthreads();
    int h = (i >> 13) & 7;   // block spans 256 tokens of one (b,h)
    if (lh[tid]) atomicAdd(&hist[h * 256 + tid], lh[tid]);
}

__global__ __launch_bounds__(256) void k3_scan(const unsigned int* __restrict__ hist,
                                               unsigned int* __restrict__ offs,
                                               unsigned int* __restrict__ cursor) {
    __shared__ unsigned int ps[256];
    const int tid = threadIdx.x;
    unsigned int loc[8];
    unsigned s = 0;
    #pragma unroll
    for (int k = 0; k < 8; k++) { loc[k] = hist[tid * 8 + k]; s += loc[k]; }
    ps[tid] = s;
    __syncthreads();
    for (int off = 1; off < 256; off <<= 1) {
        unsigned v = (tid >= off) ? ps[tid - off] : 0;
        __syncthreads();
        ps[tid] += v;
        __syncthreads();
    }
    unsigned base = ps[tid] - s;  // exclusive
    #pragma unroll
    for (int k = 0; k < 8; k++) {
        offs[tid * 8 + k] = base;
        cursor[tid * 8 + k] = base;
        base += loc[k];
    }
    if (tid == 255) offs[2048] = ps[255];
}

__global__ __launch_bounds__(256) void k3_scatter(const int* __restrict__ buckets,
                                                  unsigned int* __restrict__ cursor,
                                                  unsigned int* __restrict__ sortedTok) {
    int i = blockIdx.x * 256 + threadIdx.x;
    int bk = buckets[i];
    int h = (i >> 13) & 7, b = i >> 16, l = i & 8191;
    unsigned pos = atomicAdd(&cursor[h * 256 + bk], 1u);
    sortedTok[pos] = (unsigned)((b << 13) | l);
}

// one block per (h,c) bin; 4 waves; each wave batches 4 independent row loads per iter
__global__ __launch_bounds__(256) void k3_gather(const float* __restrict__ x,
                                                 const float* __restrict__ means,
                                                 const unsigned int* __restrict__ offs,
                                                 const unsigned int* __restrict__ sortedTok,
                                                 float* __restrict__ outMeans) {
    __shared__ float part[4][64];
    const int tid = threadIdx.x;
    const int w = tid >> 6, d = tid & 63;
    const int bin = blockIdx.x;
    const int h = bin >> 8, cc = bin & 255;
    const unsigned s0 = offs[bin], s1 = offs[bin + 1];
    const int n = (int)(s1 - s0);
    const unsigned* st = sortedTok + s0;

    float a0 = 0.f, a1 = 0.f, a2 = 0.f, a3 = 0.f;
    for (int j = w * 4; j < n; j += 16) {
        int rem = n - j;                 // wave-uniform
        unsigned e0 = st[j];
        unsigned e1 = (rem > 1) ? st[j + 1] : e0;
        unsigned e2 = (rem > 2) ? st[j + 2] : e0;
        unsigned e3 = (rem > 3) ? st[j + 3] : e0;
        size_t r0 = (((size_t)((e0 >> 13) * Hh + h)) * Ll + (e0 & 8191)) * Dd + d;
        size_t r1 = (((size_t)((e1 >> 13) * Hh + h)) * Ll + (e1 & 8191)) * Dd + d;
        size_t r2 = (((size_t)((e2 >> 13) * Hh + h)) * Ll + (e2 & 8191)) * Dd + d;
        size_t r3 = (((size_t)((e3 >> 13) * Hh + h)) * Ll + (e3 & 8191)) * Dd + d;
        float v0 = x[r0];
        float v1 = (rem > 1) ? x[r1] : 0.f;
        float v2 = (rem > 2) ? x[r2] : 0.f;
        float v3 = (rem > 3) ? x[r3] : 0.f;
        a0 += v0; a1 += v1; a2 += v2; a3 += v3;
    }
    part[w][d] = (a0 + a1) + (a2 + a3);
    __syncthreads();
    if (tid < 64) {
        float s = part[0][d] + part[1][d] + part[2][d] + part[3][d];
        float t = s * s;
        #pragma unroll
        for (int off = 32; off; off >>= 1) t += __shfl_xor(t, off);
        float nrm = sqrtf(t);
        float outv = (n == 0) ? means[((size_t)(h * Cc + cc)) * Dd + d]
                              : s / fmaxf(nrm, 1e-12f);
        outMeans[((size_t)(h * Cc + cc)) * Dd + d] = outv;
    }
}

// ---------------- k4: loss reduction ----------------
__global__ __launch_bounds__(256) void k4_loss(const float* __restrict__ lossP,
                                               float* __restrict__ out) {
    __shared__ float red[256];
    const int tid = threadIdx.x;
    float s = 0.f;
    for (int i = tid; i < Bb * Hh * (Ll / TL); i += 256) s += lossP[i];
    red[tid] = s;
    __syncthreads();
    for (int off = 128; off; off >>= 1) {
        if (tid < off) red[tid] += red[tid + off];
        __syncthreads();
    }
    if (tid == 0)
        out[(size_t)Bb * Hh * Cc * Ww] = red[0] * (1e-4f / (float)((size_t)Bb * Hh * Ll * Dd));
}

extern "C" void kernel_launch(void* const* d_in, const int* in_sizes, int n_in,
                              void* d_out, int out_size, void* d_ws, size_t ws_size,
                              hipStream_t stream) {
    (void)in_sizes; (void)n_in; (void)out_size;
    const float* x = (const float*)d_in[0];
    const float* means = (const float*)d_in[1];
    float* out = (float*)d_out;

    char* ws = (char*)d_ws;
    float* lossP = (float*)ws;                              // 2048 floats (8 KB)
    int* buckets = (int*)(ws + 8192);                       // 1 MB
    unsigned int* hist = (unsigned int*)(ws + 8192 + 1048576);       // 2048
    unsigned int* offs = hist + 2048;                       // 2049
    unsigned int* cursor = offs + 2049;                     // 2048
    unsigned int* sortedTok = cursor + 2048;                // 262144 (1 MB)
    size_t base = 8192 + 1048576 + 4ull * (2048 + 2049 + 2048) + 4ull * 262144;
    base = (base + 255) & ~255ull;
    float* distT = (float*)(ws + base);
    const size_t perPlane = (size_t)Cc * Ll * 4;            // 8 MB per (h) plane

    // bStep fixed at 1 so each 64 MB distT stays L3-warm between k1(b) and k2(b)
    int hStep = 8;
    while (hStep > 1 && base + (size_t)hStep * perPlane > ws_size) hStep >>= 1;

    hipMemsetAsync(hist, 0, 2048 * 4, stream);

    const int IDXN = Bb * Hh * Cc * Ww;  // 262144
    for (int b = 0; b < Bb; b++) {
        for (int h0 = 0; h0 < Hh; h0 += hStep) {
            k1_gemm<<<dim3(Ll / TL, hStep), 256, 0, stream>>>(x, means, distT, buckets, lossP, b, h0);
            k2_topk<<<dim3(Cc, hStep), 256, 0, stream>>>(distT, out, b, h0);
        }
    }
    k3_hist<<<1024, 256, 0, stream>>>(buckets, hist);
    k3_scan<<<1, 256, 0, stream>>>(hist, offs, cursor);
    k3_scatter<<<1024, 256, 0, stream>>>(buckets, cursor, sortedTok);
    k3_gather<<<Hh * Cc, 256, 0, stream>>>(x, means, offs, sortedTok, out + IDXN + 1);
    k4_loss<<<1, 256, 0, stream>>>(lossP, out);
}